// Round 1
// baseline (748.251 us; speedup 1.0000x reference)
//
#include <hip/hip_runtime.h>
#include <math.h>

#define BATCH    16384
#define N_SPARSE 26
#define N_DENSE  13
#define VOCAB    100000
#define EMB      64

// One 64-lane wave per batch row; lane index == embedding dimension.
// Each emb2 gather: 64 lanes x 4B = 256B contiguous = one coalesced load,
// exactly one embedding row. 26 independent gathers in flight per wave.
__global__ __launch_bounds__(256) void fm_mtl_kernel(
    const int*   __restrict__ sparse,    // [B, 26]
    const float* __restrict__ dense,     // [B, 13]
    const float* __restrict__ emb1,      // [26, V, 1]
    const float* __restrict__ emb2,      // [26, V, 64]
    const float* __restrict__ W_dense,   // [13, 1]
    const float* __restrict__ b_dense,   // [1]
    const float* __restrict__ W_finish,  // [1,1]
    const float* __restrict__ b_finish,  // [1]
    const float* __restrict__ W_like,    // [1,1]
    const float* __restrict__ b_like,    // [1]
    float*       __restrict__ out)       // [2*B] : finish ++ like
{
    const int gtid = blockIdx.x * blockDim.x + threadIdx.x;
    const int row  = gtid >> 6;          // wave id = batch row
    const int lane = threadIdx.x & 63;
    if (row >= BATCH) return;

    // Per-lane scalar contributions:
    //  lanes 0..25: emb1 gather (lin_sparse), lanes 0..12 also dense*W_dense
    int   idx_f       = 0;
    float scalar_part = 0.0f;
    if (lane < N_SPARSE) {
        idx_f       = sparse[row * N_SPARSE + lane];
        scalar_part = emb1[lane * VOCAB + idx_f];
    }
    if (lane < N_DENSE) {
        scalar_part += dense[row * N_DENSE + lane] * W_dense[lane];
    }

    // FM second order: lane e accumulates summed[e] and sum of squares.
    float sum_e   = 0.0f;
    float sumsq_e = 0.0f;
    #pragma unroll
    for (int f = 0; f < N_SPARSE; ++f) {
        int idx = __shfl(idx_f, f);      // broadcast field f's index
        float v = emb2[((size_t)f * VOCAB + (size_t)idx) * EMB + lane];
        sum_e   += v;
        sumsq_e += v * v;
    }

    // Per-lane value to reduce: 0.5*(summed^2 - squared) + first-order bits.
    float val = 0.5f * (sum_e * sum_e - sumsq_e) + scalar_part;

    // 64-lane butterfly reduction.
    #pragma unroll
    for (int off = 32; off > 0; off >>= 1)
        val += __shfl_down(val, off);

    if (lane == 0) {
        float logits = val + b_dense[0];
        float zf = logits * W_finish[0] + b_finish[0];
        float zl = logits * W_like[0]   + b_like[0];
        out[row]         = 1.0f / (1.0f + __expf(-zf));  // finish
        out[BATCH + row] = 1.0f / (1.0f + __expf(-zl));  // like
    }
}

extern "C" void kernel_launch(void* const* d_in, const int* in_sizes, int n_in,
                              void* d_out, int out_size, void* d_ws, size_t ws_size,
                              hipStream_t stream) {
    const int*   sparse   = (const int*)  d_in[0];
    const float* dense    = (const float*)d_in[1];
    const float* emb1     = (const float*)d_in[2];
    const float* emb2     = (const float*)d_in[3];
    const float* W_dense  = (const float*)d_in[4];
    const float* b_dense  = (const float*)d_in[5];
    const float* W_finish = (const float*)d_in[6];
    const float* b_finish = (const float*)d_in[7];
    const float* W_like   = (const float*)d_in[8];
    const float* b_like   = (const float*)d_in[9];
    float* out = (float*)d_out;

    // 1 wave per row, 4 waves per 256-thread block -> 4096 blocks.
    const int threads = 256;
    const int blocks  = (BATCH * 64) / threads;
    fm_mtl_kernel<<<blocks, threads, 0, stream>>>(
        sparse, dense, emb1, emb2,
        W_dense, b_dense, W_finish, b_finish, W_like, b_like, out);
}